// Round 1
// baseline (90.478 us; speedup 1.0000x reference)
//
#include <hip/hip_runtime.h>
#include <math.h>

// Problem constants
#define Bn 8
#define Cn 64
#define Hn 128
#define Wn 128
#define Rn 4

__device__ __forceinline__ float leaky(float x) { return x >= 0.f ? x : 0.1f * x; }

// ---------------------------------------------------------------------------
// Kernel A: per-batch precompute of dynamic depthwise kernels + channel attn
//   kern_g[b][c][r][9] = kflat[b,r,c*9+kk]  (b*2304 + c*36 + r*9 + kk)
//   att_g [b][r][c]    = sigmoid(sum_i a[b,r*16+i] * w_ca2[r,c,i])
// ---------------------------------------------------------------------------
__global__ __launch_bounds__(256) void precomp_kernel(
    const float* __restrict__ deg, const float* __restrict__ w_k1,
    const float* __restrict__ w_k2, const float* __restrict__ w_ca1,
    const float* __restrict__ w_ca2, float* __restrict__ kern_g,
    float* __restrict__ att_g)
{
    const int b = blockIdx.x, tid = threadIdx.x;
    __shared__ float y_s[64], a_s[64];
    if (tid < 64) {
        float sy = 0.f, sa = 0.f;
#pragma unroll 8
        for (int j = 0; j < 64; ++j) {
            float d = deg[b * 64 + j];
            sy += d * w_k1[tid * 64 + j];
            sa += d * w_ca1[tid * 64 + j];
        }
        y_s[tid] = leaky(sy);
        a_s[tid] = leaky(sa);
    }
    __syncthreads();
    // kern: 64*4*9 = 2304 values, each a 16-MAC dot
    for (int f = tid; f < Cn * Rn * 9; f += 256) {
        int c = f / 36;
        int j = f - c * 36;
        int r = j / 9;
        int kk = j - r * 9;
        int o = c * 9 + kk;                      // index into (576) dim of w_k2
        const float* wp = &w_k2[(r * 576 + o) * 16];
        const float* yp = &y_s[r * 16];
        float s = 0.f;
#pragma unroll
        for (int i = 0; i < 16; ++i) s += yp[i] * wp[i];
        kern_g[b * 2304 + f] = s;
    }
    // att: 4*64 = 256 values
    {
        int r = tid >> 6, o = tid & 63;
        const float* wp = &w_ca2[(r * 64 + o) * 16];
        const float* ap = &a_s[r * 16];
        float s = 0.f;
#pragma unroll
        for (int i = 0; i < 16; ++i) s += ap[i] * wp[i];
        att_g[b * 256 + tid] = 1.f / (1.f + expf(-s));
    }
}

// ---------------------------------------------------------------------------
// Main kernel: one block per (b, h) row. 256 threads.
//   phase 0: stage w_conv^T, kern[b], att[b] in LDS; compute r1/r2 per w
//   phase 1: t[c][w] = leaky(depthwise3x3(x0, kern[b,c,r1])) into LDS
//   phase 2: out[o][w] = sum_c t[c][w]*w_conv[o,c] + b_conv[o] + x0[o,w]*att[r2,o]
// ---------------------------------------------------------------------------
__global__ __launch_bounds__(256) void da_main(
    const float* __restrict__ x0, const float* __restrict__ q_map,
    const float* __restrict__ w_conv, const float* __restrict__ b_conv,
    const float* __restrict__ w_g1, const float* __restrict__ b_g1,
    const float* __restrict__ w_g2, const float* __restrict__ b_g2,
    const float* __restrict__ kern_g, const float* __restrict__ att_g,
    float* __restrict__ out)
{
    __shared__ __align__(16) float t_lds[Cn * Wn];          // 32 KB
    __shared__ float xstage[8][3][Wn + 2];                   // 12.2 KB
    __shared__ float kern_lds[Cn * 37];                      // 9.25 KB (stride 37)
    __shared__ __align__(16) float wconv_lds[Cn * 72];       // 18 KB  (t: [c][o], stride 72)
    __shared__ float att_lds[Rn * 65];                       // 1 KB   (stride 65)
    __shared__ int ridx1[Wn], ridx2[Wn];                     // 1 KB

    const int tid = threadIdx.x;
    const int ob = blockIdx.x;
    // XCD-aware swizzle: XCD i gets b = i, h = 0..127 (contiguous rows -> L2 halo reuse)
    const int sb = ((ob & 7) << 7) | (ob >> 3);
    const int b = sb >> 7;
    const int h = sb & 127;

    // ---- phase 0: LDS staging ----
    for (int f = tid; f < 2304; f += 256) {
        int c = f / 36;
        int j = f - c * 36;
        kern_lds[c * 37 + j] = kern_g[b * 2304 + f];
    }
    for (int f = tid; f < 4096; f += 256) {
        int o = f >> 6, c = f & 63;
        wconv_lds[c * 72 + o] = w_conv[f];                  // transpose on load
    }
    {
        int r = tid >> 6, c = tid & 63;
        att_lds[r * 65 + c] = att_g[b * 256 + tid];
    }
    // region routing: waves 0-1 compute r1 (w_g1), waves 2-3 compute r2 (w_g2)
    {
        int w = tid & 127;
        const float* wg = (tid < 128) ? w_g1 : w_g2;
        const float* bg = (tid < 128) ? b_g1 : b_g2;
        float q[9];
#pragma unroll
        for (int dh = 0; dh < 3; ++dh) {
            int row = h - 1 + dh;
#pragma unroll
            for (int dw = 0; dw < 3; ++dw) {
                int col = w - 1 + dw;
                q[dh * 3 + dw] = (row >= 0 && row < Hn && col >= 0 && col < Wn)
                                     ? q_map[(b * Hn + row) * Wn + col] : 0.f;
            }
        }
        float best = -1e30f; int bi = 0;
#pragma unroll
        for (int r = 0; r < Rn; ++r) {
            float s = bg[r];
#pragma unroll
            for (int k = 0; k < 9; ++k) s += q[k] * wg[r * 9 + k];
            if (s > best) { best = s; bi = r; }             // strict > == first argmax
        }
        if (tid < 128) ridx1[w] = bi; else ridx2[w] = bi;
    }
    __syncthreads();

    // ---- phase 1: depthwise conv with selected region kernel ----
    const int w = tid & 127;
    const int half = tid >> 7;
    const int r1 = ridx1[w];
    for (int g = 0; g < 8; ++g) {
        if (g) __syncthreads();                             // prev group's reads done
        // stage 8 channels x 3 rows of x0 (coalesced 256B loads)
#pragma unroll
        for (int i = 0; i < 12; ++i) {
            int flat = i * 256 + tid;                       // 0..3071
            int idx = flat >> 7;                            // 0..23 = (cL,row)
            int ww = flat & 127;
            int cL = idx / 3, r3 = idx - cL * 3;
            int row = h - 1 + r3;
            float v = 0.f;
            if (row >= 0 && row < Hn)
                v = x0[((b * Cn + g * 8 + cL) * Hn + row) * Wn + ww];
            xstage[cL][r3][ww + 1] = v;
        }
        if (tid < 48) {                                     // horizontal zero pad
            int p = tid >> 1, e = tid & 1;
            int cL = p / 3, r3 = p - cL * 3;
            xstage[cL][r3][e ? (Wn + 1) : 0] = 0.f;
        }
        __syncthreads();
#pragma unroll
        for (int j = 0; j < 4; ++j) {
            int cIdx = half * 4 + j;
            int c = g * 8 + cIdx;
            const float* kp = &kern_lds[c * 37 + r1 * 9];
            float acc = 0.f;
#pragma unroll
            for (int kh = 0; kh < 3; ++kh)
#pragma unroll
                for (int kw = 0; kw < 3; ++kw)
                    acc += xstage[cIdx][kh][w + kw] * kp[kh * 3 + kw];
            t_lds[c * Wn + w] = leaky(acc);
        }
    }
    __syncthreads();

    // ---- phase 2: 64-channel mix + CA branch + store ----
    const int wq = tid & 31, og = tid >> 5;
    const int w0 = wq * 4, o0 = og * 8;

    float acc[4][8];
#pragma unroll
    for (int i = 0; i < 4; ++i)
#pragma unroll
        for (int j = 0; j < 8; ++j) acc[i][j] = 0.f;

    for (int c = 0; c < 64; ++c) {
        float4 tv = *(const float4*)&t_lds[c * Wn + w0];
        float4 wa = *(const float4*)&wconv_lds[c * 72 + o0];
        float4 wb = *(const float4*)&wconv_lds[c * 72 + o0 + 4];
        float t4[4] = {tv.x, tv.y, tv.z, tv.w};
        float wv[8] = {wa.x, wa.y, wa.z, wa.w, wb.x, wb.y, wb.z, wb.w};
#pragma unroll
        for (int i = 0; i < 4; ++i)
#pragma unroll
            for (int j = 0; j < 8; ++j) acc[i][j] += t4[i] * wv[j];
    }

    int r2v[4];
#pragma unroll
    for (int i = 0; i < 4; ++i) r2v[i] = ridx2[w0 + i];

#pragma unroll
    for (int j = 0; j < 8; ++j) {
        int o = o0 + j;
        float bc = b_conv[o];
        const float4 xv = *(const float4*)&x0[((b * Cn + o) * Hn + h) * Wn + w0];
        float4 res;
        res.x = acc[0][j] + bc + xv.x * att_lds[r2v[0] * 65 + o];
        res.y = acc[1][j] + bc + xv.y * att_lds[r2v[1] * 65 + o];
        res.z = acc[2][j] + bc + xv.z * att_lds[r2v[2] * 65 + o];
        res.w = acc[3][j] + bc + xv.w * att_lds[r2v[3] * 65 + o];
        *(float4*)&out[((b * Cn + o) * Hn + h) * Wn + w0] = res;
    }
}

// ---------------------------------------------------------------------------
extern "C" void kernel_launch(void* const* d_in, const int* in_sizes, int n_in,
                              void* d_out, int out_size, void* d_ws, size_t ws_size,
                              hipStream_t stream)
{
    const float* x0     = (const float*)d_in[0];
    const float* deg    = (const float*)d_in[1];
    const float* q_map  = (const float*)d_in[2];
    const float* w_k1   = (const float*)d_in[3];
    const float* w_k2   = (const float*)d_in[4];
    const float* w_conv = (const float*)d_in[5];
    const float* b_conv = (const float*)d_in[6];
    const float* w_ca1  = (const float*)d_in[7];
    const float* w_ca2  = (const float*)d_in[8];
    const float* w_g1   = (const float*)d_in[9];
    const float* b_g1   = (const float*)d_in[10];
    const float* w_g2   = (const float*)d_in[11];
    const float* b_g2   = (const float*)d_in[12];
    float* outp   = (float*)d_out;
    float* kern_g = (float*)d_ws;                 // 8*2304 floats
    float* att_g  = kern_g + Bn * Cn * Rn * 9;    // 8*256  floats

    precomp_kernel<<<Bn, 256, 0, stream>>>(deg, w_k1, w_k2, w_ca1, w_ca2, kern_g, att_g);
    da_main<<<Bn * Hn, 256, 0, stream>>>(x0, q_map, w_conv, b_conv,
                                         w_g1, b_g1, w_g2, b_g2,
                                         kern_g, att_g, outp);
}

// Round 2
// 77.172 us; speedup vs baseline: 1.1724x; 1.1724x over previous
//
#include <hip/hip_runtime.h>
#include <math.h>

// Problem constants
#define Bn 8
#define Cn 64
#define Hn 128
#define Wn 128
#define Rn 4

__device__ __forceinline__ float leaky(float x) { return x >= 0.f ? x : 0.1f * x; }

// ---------------------------------------------------------------------------
// Kernel A: per-batch precompute of dynamic depthwise kernels + channel attn,
// plus (block Bn) a transpose of w_conv -> w_convT[c][o] for scalar loads.
//   kern_g[b][c][r][9] laid out as b*2304 + c*36 + r*9 + kk
//   att_g [b][r][c]    = sigmoid(sum_i a[b,r*16+i] * w_ca2[r,c,i])
// ---------------------------------------------------------------------------
__global__ __launch_bounds__(256) void precomp_kernel(
    const float* __restrict__ deg, const float* __restrict__ w_k1,
    const float* __restrict__ w_k2, const float* __restrict__ w_ca1,
    const float* __restrict__ w_ca2, const float* __restrict__ w_conv,
    float* __restrict__ kern_g, float* __restrict__ att_g,
    float* __restrict__ wT)
{
    const int tid = threadIdx.x;
    if (blockIdx.x == Bn) {                       // transpose w_conv (tiny)
        for (int f = tid; f < Cn * Cn; f += 256) {
            int o = f >> 6, c = f & 63;
            wT[c * 64 + o] = w_conv[f];
        }
        return;
    }
    const int b = blockIdx.x;
    __shared__ float y_s[64], a_s[64];
    if (tid < 64) {
        float sy = 0.f, sa = 0.f;
#pragma unroll 8
        for (int j = 0; j < 64; ++j) {
            float d = deg[b * 64 + j];
            sy += d * w_k1[tid * 64 + j];
            sa += d * w_ca1[tid * 64 + j];
        }
        y_s[tid] = leaky(sy);
        a_s[tid] = leaky(sa);
    }
    __syncthreads();
    // kern: 64*4*9 = 2304 values, each a 16-MAC dot
    for (int f = tid; f < Cn * Rn * 9; f += 256) {
        int c = f / 36;
        int j = f - c * 36;
        int r = j / 9;
        int kk = j - r * 9;
        int o = c * 9 + kk;                      // index into (576) dim of w_k2
        const float* wp = &w_k2[(r * 576 + o) * 16];
        const float* yp = &y_s[r * 16];
        float s = 0.f;
#pragma unroll
        for (int i = 0; i < 16; ++i) s += yp[i] * wp[i];
        kern_g[b * 2304 + f] = s;
    }
    // att: 4*64 = 256 values
    {
        int r = tid >> 6, o = tid & 63;
        const float* wp = &w_ca2[(r * 64 + o) * 16];
        const float* ap = &a_s[r * 16];
        float s = 0.f;
#pragma unroll
        for (int i = 0; i < 16; ++i) s += ap[i] * wp[i];
        att_g[b * 256 + tid] = 1.f / (1.f + expf(-s));
    }
}

// ---------------------------------------------------------------------------
// Main kernel: one block per (b, h) row. 256 threads, 2 barriers total.
//   phase 0: stage kern[b] ([c][r][12] layout), att[b]; compute r1/r2 per w
//   phase 1: barrier-free depthwise: each thread owns column w, 32 channels;
//            neighbors via shfl; writes t[c][w] to LDS
//   phase 2: wave v owns o in [16v,16v+16); per c: uniform s_load of wT row
//            segment + float2 t read; fused CA branch + bias + store
// ---------------------------------------------------------------------------
__global__ __launch_bounds__(256) void da_main(
    const float* __restrict__ x0, const float* __restrict__ q_map,
    const float* __restrict__ wT, const float* __restrict__ b_conv,
    const float* __restrict__ w_g1, const float* __restrict__ b_g1,
    const float* __restrict__ w_g2, const float* __restrict__ b_g2,
    const float* __restrict__ kern_g, const float* __restrict__ att_g,
    float* __restrict__ out)
{
    __shared__ __align__(16) float t_lds[Cn * Wn];            // 32 KB
    __shared__ __align__(16) float kern_lds[Cn * Rn * 12];    // 12 KB
    __shared__ float att_lds[Rn * 65];                        // 1 KB
    __shared__ int ridx1[Wn], ridx2[Wn];                      // 1 KB

    const int tid = threadIdx.x;
    const int ob = blockIdx.x;
    // XCD-aware swizzle: XCD i gets batch i (4 MB image == one L2); consecutive
    // h are 8 dispatch slots apart -> halo rows L2-co-resident.
    const int sb = ((ob & 7) << 7) | (ob >> 3);
    const int b = sb >> 7;
    const int h = sb & 127;

    // ---- phase 0 ----
    for (int f = tid; f < Cn * Rn * 9; f += 256) {
        int c = f / 36;
        int j = f - c * 36;
        int r = j / 9;
        int kk = j - r * 9;
        kern_lds[c * 48 + r * 12 + kk] = kern_g[b * 2304 + f];
    }
    {
        int r = tid >> 6, c = tid & 63;
        att_lds[r * 65 + c] = att_g[b * 256 + tid];
    }
    // region routing: waves 0-1 compute r1 (w_g1), waves 2-3 compute r2 (w_g2)
    {
        int w = tid & 127;
        const float* wg = (tid < 128) ? w_g1 : w_g2;
        const float* bg = (tid < 128) ? b_g1 : b_g2;
        float q[9];
#pragma unroll
        for (int dh = 0; dh < 3; ++dh) {
            int row = h - 1 + dh;
#pragma unroll
            for (int dw = 0; dw < 3; ++dw) {
                int col = w - 1 + dw;
                q[dh * 3 + dw] = (row >= 0 && row < Hn && col >= 0 && col < Wn)
                                     ? q_map[(b * Hn + row) * Wn + col] : 0.f;
            }
        }
        float best = -1e30f; int bi = 0;
#pragma unroll
        for (int r = 0; r < Rn; ++r) {
            float s = bg[r];
#pragma unroll
            for (int k = 0; k < 9; ++k) s += q[k] * wg[r * 9 + k];
            if (s > best) { best = s; bi = r; }             // strict > == first argmax
        }
        if (tid < 128) ridx1[w] = bi; else ridx2[w] = bi;
    }
    __syncthreads();

    // ---- phase 1: barrier-free depthwise conv ----
    const int w = tid & 127;
    const int half = tid >> 7;          // 0: c 0-31, 1: c 32-63
    const int lane = tid & 63;
    const int r1 = ridx1[w];
    const bool okm = (h - 1) >= 0;
    const bool okp = (h + 1) < Hn;
#pragma unroll 2
    for (int ci = 0; ci < 32; ++ci) {
        const int c = half * 32 + ci;
        const float* xc = x0 + ((b * Cn + c) * Hn + h) * Wn + w;
        float vm = okm ? xc[-Wn] : 0.f;
        float v0 = xc[0];
        float vp = okp ? xc[Wn] : 0.f;
        float lm = __shfl_up(vm, 1), l0 = __shfl_up(v0, 1), lp = __shfl_up(vp, 1);
        float rm = __shfl_down(vm, 1), r0 = __shfl_down(v0, 1), rp = __shfl_down(vp, 1);
        if (lane == 0) {                 // left edge of this wave's w-range
            if (w == 0) { lm = 0.f; l0 = 0.f; lp = 0.f; }
            else { lm = okm ? xc[-1 - Wn] : 0.f; l0 = xc[-1]; lp = okp ? xc[-1 + Wn] : 0.f; }
        }
        if (lane == 63) {                // right edge
            if (w == 127) { rm = 0.f; r0 = 0.f; rp = 0.f; }
            else { rm = okm ? xc[1 - Wn] : 0.f; r0 = xc[1]; rp = okp ? xc[1 + Wn] : 0.f; }
        }
        const float* kp = &kern_lds[c * 48 + r1 * 12];
        float4 ka = *(const float4*)kp;          // k0..k3
        float4 kb = *(const float4*)(kp + 4);    // k4..k7
        float k8 = kp[8];
        float acc = lm * ka.x + vm * ka.y + rm * ka.z
                  + l0 * ka.w + v0 * kb.x + r0 * kb.y
                  + lp * kb.z + vp * kb.w + rp * k8;
        t_lds[c * Wn + w] = leaky(acc);
    }
    __syncthreads();

    // ---- phase 2: channel mix (o wave-uniform -> scalar weight loads) ----
    const int wv = __builtin_amdgcn_readfirstlane(tid >> 6);  // wave id 0..3
    const int o0 = wv * 16;
    const int w0 = lane * 2;

    float accA[16], accB[16];
#pragma unroll
    for (int o = 0; o < 16; ++o) { accA[o] = 0.f; accB[o] = 0.f; }

#pragma unroll 4
    for (int c = 0; c < 64; ++c) {
        float2 tv = *(const float2*)&t_lds[c * Wn + w0];
        const float* wr = wT + c * 64 + o0;      // uniform -> s_load
#pragma unroll
        for (int o = 0; o < 16; ++o) {
            float wv_ = wr[o];
            accA[o] += tv.x * wv_;
            accB[o] += tv.y * wv_;
        }
    }

    const int r2a = ridx2[w0], r2b = ridx2[w0 + 1];
#pragma unroll
    for (int o = 0; o < 16; ++o) {
        const int oo = o0 + o;
        const float bc = b_conv[oo];
        const float2 xv = *(const float2*)&x0[((b * Cn + oo) * Hn + h) * Wn + w0];
        float2 res;
        res.x = accA[o] + bc + xv.x * att_lds[r2a * 65 + oo];
        res.y = accB[o] + bc + xv.y * att_lds[r2b * 65 + oo];
        *(float2*)&out[((b * Cn + oo) * Hn + h) * Wn + w0] = res;
    }
}

// ---------------------------------------------------------------------------
extern "C" void kernel_launch(void* const* d_in, const int* in_sizes, int n_in,
                              void* d_out, int out_size, void* d_ws, size_t ws_size,
                              hipStream_t stream)
{
    const float* x0     = (const float*)d_in[0];
    const float* deg    = (const float*)d_in[1];
    const float* q_map  = (const float*)d_in[2];
    const float* w_k1   = (const float*)d_in[3];
    const float* w_k2   = (const float*)d_in[4];
    const float* w_conv = (const float*)d_in[5];
    const float* b_conv = (const float*)d_in[6];
    const float* w_ca1  = (const float*)d_in[7];
    const float* w_ca2  = (const float*)d_in[8];
    const float* w_g1   = (const float*)d_in[9];
    const float* b_g1   = (const float*)d_in[10];
    const float* w_g2   = (const float*)d_in[11];
    const float* b_g2   = (const float*)d_in[12];
    float* outp   = (float*)d_out;
    float* kern_g = (float*)d_ws;                 // 8*2304 floats
    float* att_g  = kern_g + Bn * Cn * Rn * 9;    // 8*256  floats
    float* wT     = att_g + Bn * 256;             // 4096   floats

    precomp_kernel<<<Bn + 1, 256, 0, stream>>>(deg, w_k1, w_k2, w_ca1, w_ca2,
                                               w_conv, kern_g, att_g, wT);
    da_main<<<Bn * Hn, 256, 0, stream>>>(x0, q_map, wT, b_conv,
                                         w_g1, b_g1, w_g2, b_g2,
                                         kern_g, att_g, outp);
}